// Round 4
// baseline (194.757 us; speedup 1.0000x reference)
//
#include <hip/hip_runtime.h>
#include <cfloat>

#define NB 4096           // nodes per batch
#define FD 64             // feature dim
#define EPT 16            // elements per thread = NB / 256
#define LRELU_ALPHA 0.2f
#define CAND_CAP 256

__device__ __forceinline__ unsigned long long shfl_xor_u64(unsigned long long v, int m) {
    int lo = __shfl_xor((int)(unsigned int)(v & 0xFFFFFFFFull), m, 64);
    int hi = __shfl_xor((int)(unsigned int)(v >> 32), m, 64);
    return ((unsigned long long)(unsigned int)hi << 32) | (unsigned int)lo;
}

// Fully fused: kNN select (exact, jax.lax.top_k stable order) + attention.
// Algebraic refactors (smooth path only): f1 = x@(W@a1), f2 = x@(W@a2),
// h = (attn@x)@W — so Wh is never materialized and there is no prep kernel.
__global__ __launch_bounds__(256) void gat_fused(
    const float* __restrict__ x, const float* __restrict__ pos,
    const float* __restrict__ W, const float* __restrict__ a,
    const float* __restrict__ Wp, const float* __restrict__ bp,
    const int* __restrict__ kptr, float* __restrict__ out)
{
    __shared__ float sW[FD * 65];                  // W, stride-65 padded
    __shared__ unsigned long long upool[672];      // phase A: wm[84] | cand[256]
                                                   // phase B: xs[21][64] floats
    __shared__ float sWa1[FD], sWa2[FD];
    __shared__ unsigned long long sT;
    __shared__ unsigned int cnt;
    __shared__ int idx21[32];                      // [0]=self n, [1..k]=nbrs
    __shared__ float aw[32];
    __shared__ float sf1;
    __shared__ float gs[FD];
    __shared__ float part[4][FD];

    unsigned long long* wm   = upool;              // 84 entries
    unsigned long long* cand = upool + 84;         // 256 entries
    float (*xs)[FD] = (float(*)[FD])upool;         // 21*64 floats = 5376 B

    const int tid = threadIdx.x;
    const int lane = tid & 63, wave = tid >> 6;
    const int row = blockIdx.x;                    // b*4096 + n
    const int b = row >> 12, n = row & (NB - 1);
    const float* posb = pos + (size_t)b * NB * 3;

    // stage W -> LDS (16 KB); first read is much later (after B1..B4)
    #pragma unroll
    for (int t = 0; t < 16; ++t) {
        const int e = t * 256 + tid;
        sW[(e >> 6) * 65 + (e & 63)] = W[e];
    }
    if (tid == 0) cnt = 0;

    const float qx = posb[n * 3 + 0];
    const float qy = posb[n * 3 + 1];
    const float qz = posb[n * 3 + 2];
    // Exact numpy op order (no contraction) -> d2 bits match the reference,
    // so the top-k SET and its stable (d2, idx) order match bit-exactly.
    const float sqn = __fadd_rn(__fadd_rn(__fmul_rn(qx, qx), __fmul_rn(qy, qy)),
                                __fmul_rn(qz, qz));

    unsigned int key[EPT];
    unsigned long long pmin = ~0ull;
    #pragma unroll
    for (int t = 0; t < EPT; ++t) {
        const int m = t * 256 + tid;
        const float px = posb[m * 3 + 0];
        const float py = posb[m * 3 + 1];
        const float pz = posb[m * 3 + 2];
        const float sqm = __fadd_rn(__fadd_rn(__fmul_rn(px, px), __fmul_rn(py, py)),
                                    __fmul_rn(pz, pz));
        const float dot = __fadd_rn(__fadd_rn(__fmul_rn(qx, px), __fmul_rn(qy, py)),
                                    __fmul_rn(qz, pz));
        const float d2 = __fsub_rn(__fadd_rn(sqn, sqm), __fmul_rn(2.0f, dot));
        const unsigned int u = __float_as_uint(d2);
        const unsigned int kk = u ^ ((unsigned int)((int)u >> 31) | 0x80000000u);
        key[t] = kk;
        const unsigned long long pk = ((unsigned long long)kk << 12) | (unsigned int)m;
        pmin = pk < pmin ? pk : pmin;
    }

    // wave-level bitonic sort of the 64 per-thread minima (registers only)
    unsigned long long v = pmin;
    #pragma unroll
    for (int kk2 = 2; kk2 <= 64; kk2 <<= 1) {
        #pragma unroll
        for (int j = kk2 >> 1; j > 0; j >>= 1) {
            const unsigned long long o = shfl_xor_u64(v, j);
            const bool up = ((lane & kk2) == 0);
            const bool keepMin = (((lane & j) == 0) == up);
            const unsigned long long mn = v < o ? v : o;
            const unsigned long long mx = v < o ? o : v;
            v = keepMin ? mn : mx;
        }
    }
    if (lane < 21) wm[wave * 21 + lane] = v;
    __syncthreads();                               // B1

    // exact 21st-smallest of the 256 thread-minima: provable upper bound T
    if (tid < 84) {
        const unsigned long long xv = wm[tid];
        int r = 0;
        for (int j = 0; j < 84; ++j) r += (wm[j] < xv);
        if (r == 20) sT = xv;                      // unique (pk distinct)
    }
    __syncthreads();                               // B2
    const unsigned long long T = sT;

    // compact candidates <= T (~22-45 expected; contains global top-21)
    #pragma unroll
    for (int t = 0; t < EPT; ++t) {
        const int m = t * 256 + tid;
        const unsigned long long pk = ((unsigned long long)key[t] << 12) | (unsigned int)m;
        if (pk <= T) {
            const unsigned int p = atomicAdd(&cnt, 1u);
            if (p < CAND_CAP) cand[p] = pk;
        }
    }
    __syncthreads();                               // B3

    const int k = *kptr;                           // 20
    const int K1 = k + 1;
    const int cn = cnt < (unsigned)CAND_CAP ? (int)cnt : CAND_CAP;
    if (tid < cn) {
        const unsigned long long xv = cand[tid];
        int r = 0;
        for (int j = 0; j < cn; ++j) r += (cand[j] < xv);
        // rank 0 = dropped first column; ranks 1..k = neighbors, stable order
        if (r >= 1 && r <= k) idx21[r] = (int)(xv & 0xFFFu);
    }
    if (tid == 0) idx21[0] = n;                    // query row for f1
    __syncthreads();                               // B4 (cand/wm dead after)

    // phase B: xs rows (self + neighbors) into upool; Wa1/Wa2 from sW
    for (int t = wave; t < K1; t += 4)
        xs[t][lane] = x[((size_t)((b << 12) + idx21[t]) << 6) + lane];
    if (wave == 0) {
        float s = 0.f;
        #pragma unroll
        for (int j = 0; j < FD; ++j) s = fmaf(sW[lane * 65 + j], a[j], s);
        sWa1[lane] = s;
    } else if (wave == 1) {
        float s = 0.f;
        #pragma unroll
        for (int j = 0; j < FD; ++j) s = fmaf(sW[lane * 65 + j], a[FD + j], s);
        sWa2[lane] = s;
    }
    __syncthreads();                               // B5

    // dots: t=0 -> f1 (Wa1), t>=1 -> f2_t (Wa2); butterfly reduce per wave
    for (int t = wave; t < K1; t += 4) {
        const float* wa = (t == 0) ? sWa1 : sWa2;
        float p = xs[t][lane] * wa[lane];
        #pragma unroll
        for (int off = 32; off > 0; off >>= 1) p += __shfl_down(p, off, 64);
        if (lane == 0) { if (t == 0) sf1 = p; else aw[t] = p; }
    }
    __syncthreads();                               // B6

    if (tid == 0) {
        const float f1v = sf1;
        float mx = -FLT_MAX;
        for (int t = 1; t <= k; ++t) {
            float e = f1v + aw[t];
            e = e > 0.f ? e : LRELU_ALPHA * e;
            aw[t] = e;
            mx = fmaxf(mx, e);
        }
        float Z = 0.f;
        for (int t = 1; t <= k; ++t) Z += __expf(aw[t] - mx);
        const float rz = 1.0f / Z;
        for (int t = 1; t <= k; ++t) aw[t] = __expf(aw[t] - mx) * rz;
    }
    __syncthreads();                               // B7

    // g = attn @ x  (x-space gather)
    float gp = 0.f;
    for (int t = 1 + wave; t <= k; t += 4)
        gp = fmaf(aw[t], xs[t][lane], gp);
    part[wave][lane] = gp;
    __syncthreads();                               // B8
    if (tid < FD) gs[tid] = part[0][tid] + part[1][tid] + part[2][tid] + part[3][tid];
    __syncthreads();                               // B9

    // h = g @ W  (split K across waves)
    float hp = 0.f;
    #pragma unroll
    for (int i = 0; i < 16; ++i) {
        const int kk = wave * 16 + i;
        hp = fmaf(gs[kk], sW[kk * 65 + lane], hp);
    }
    part[wave][lane] = hp;
    __syncthreads();                               // B10

    if (tid < FD) {
        float h = part[0][tid] + part[1][tid] + part[2][tid] + part[3][tid];
        float pv = fmaf(qx, Wp[0 * FD + tid],
                   fmaf(qy, Wp[1 * FD + tid],
                   fmaf(qz, Wp[2 * FD + tid], bp[tid])));
        h += pv > 0.f ? pv : 0.f;
        out[((size_t)row << 6) + tid] = h > 0.f ? h : expm1f(h);
    }
}

extern "C" void kernel_launch(void* const* d_in, const int* in_sizes, int n_in,
                              void* d_out, int out_size, void* d_ws, size_t ws_size,
                              hipStream_t stream) {
    const float* x   = (const float*)d_in[0];
    const float* pos = (const float*)d_in[1];
    const float* W   = (const float*)d_in[2];
    const float* a   = (const float*)d_in[3];
    const float* Wp  = (const float*)d_in[4];
    const float* bp  = (const float*)d_in[5];
    const int*   kp  = (const int*)d_in[6];
    float* out = (float*)d_out;

    gat_fused<<<8192, 256, 0, stream>>>(x, pos, W, a, Wp, bp, kp, out);
}

// Round 5
// 132.527 us; speedup vs baseline: 1.4696x; 1.4696x over previous
//
#include <hip/hip_runtime.h>
#include <cfloat>

#define NB 4096           // nodes per batch
#define FD 64             // feature dim
#define EPT 16            // elements per thread = NB / 256
#define LRELU_ALPHA 0.2f
#define CAND_CAP 256

__device__ __forceinline__ unsigned long long shfl_xor_u64(unsigned long long v, int m) {
    int lo = __shfl_xor((int)(unsigned int)(v & 0xFFFFFFFFull), m, 64);
    int hi = __shfl_xor((int)(unsigned int)(v >> 32), m, 64);
    return ((unsigned long long)(unsigned int)hi << 32) | (unsigned int)lo;
}

// Tiny precompute: Wa1 = W@a[:64], Wa2 = W@a[64:]  (block-invariant)
__global__ void wa_kernel(const float* __restrict__ W, const float* __restrict__ a,
                          float* __restrict__ wa) {
    const int t = threadIdx.x;            // 0..127
    const float* av = a + ((t >> 6) << 6);
    const int i = t & 63;
    float s = 0.f;
    #pragma unroll
    for (int j = 0; j < FD; ++j) s = fmaf(W[i * FD + j], av[j], s);
    wa[t] = s;
}

// Fused kNN select (exact, jax.lax.top_k stable order) + attention.
// f1/f2 via x@(W@a), h = (attn@x)@W. W never staged in LDS (L1/L2-hit reads);
// LDS kept ~7.5 KB so 8 blocks/CU stay resident (R4 lesson: big LDS killed
// occupancy 70->32% and tripled the latency-bound selection phase).
__global__ __launch_bounds__(256) void gat_fused(
    const float* __restrict__ x, const float* __restrict__ pos,
    const float* __restrict__ W, const float* __restrict__ wa,
    const float* __restrict__ Wp, const float* __restrict__ bp,
    const int* __restrict__ kptr, float* __restrict__ out)
{
    __shared__ unsigned long long upool[672];      // A: wm[84]|cand[256]; B: xs[21][64]
    __shared__ float sWa1[FD], sWa2[FD];
    __shared__ unsigned long long sT;
    __shared__ unsigned int cnt;
    __shared__ int idx21[32];                      // rank 0 = dropped col 0
    __shared__ float aw[32];
    __shared__ float sf1;
    __shared__ float gs[FD];
    __shared__ float part[4][FD];

    unsigned long long* wm   = upool;              // 84 entries
    unsigned long long* cand = upool + 84;         // 256 entries
    float (*xs)[FD] = (float(*)[FD])upool;         // 21*64 floats (phase B)

    const int tid = threadIdx.x;
    const int lane = tid & 63, wave = tid >> 6;
    const int row = blockIdx.x;                    // b*4096 + n
    const int b = row >> 12, n = row & (NB - 1);
    const float* posb = pos + (size_t)b * NB * 3;

    if (tid == 0) cnt = 0;
    if (tid < 2 * FD) { if (tid < FD) sWa1[tid] = wa[tid]; else sWa2[tid - FD] = wa[tid]; }

    const float qx = posb[n * 3 + 0];
    const float qy = posb[n * 3 + 1];
    const float qz = posb[n * 3 + 2];
    // Exact numpy op order (no contraction) -> d2 bits match the reference,
    // so the top-k SET and its stable (d2, idx) order match bit-exactly.
    const float sqn = __fadd_rn(__fadd_rn(__fmul_rn(qx, qx), __fmul_rn(qy, qy)),
                                __fmul_rn(qz, qz));

    // each thread owns 16 CONSECUTIVE nodes -> pos chunk is 192B, 16B-aligned:
    // 12 float4 loads (wave-contiguous) instead of 48 scalar loads.
    const float4* p4 = (const float4*)posb;
    unsigned int key[EPT];
    unsigned long long pmin = ~0ull;
    #pragma unroll
    for (int c = 0; c < 4; ++c) {
        const float4 a0 = p4[tid * 12 + c * 3 + 0];
        const float4 a1 = p4[tid * 12 + c * 3 + 1];
        const float4 a2 = p4[tid * 12 + c * 3 + 2];
        const float pxs[4] = {a0.x, a0.w, a1.z, a2.y};
        const float pys[4] = {a0.y, a1.x, a1.w, a2.z};
        const float pzs[4] = {a0.z, a1.y, a2.x, a2.w};
        #pragma unroll
        for (int j = 0; j < 4; ++j) {
            const int t = c * 4 + j;
            const int m = tid * EPT + t;
            const float sqm = __fadd_rn(__fadd_rn(__fmul_rn(pxs[j], pxs[j]),
                                                  __fmul_rn(pys[j], pys[j])),
                                        __fmul_rn(pzs[j], pzs[j]));
            const float dot = __fadd_rn(__fadd_rn(__fmul_rn(qx, pxs[j]),
                                                  __fmul_rn(qy, pys[j])),
                                        __fmul_rn(qz, pzs[j]));
            const float d2 = __fsub_rn(__fadd_rn(sqn, sqm), __fmul_rn(2.0f, dot));
            const unsigned int u = __float_as_uint(d2);
            const unsigned int kk = u ^ ((unsigned int)((int)u >> 31) | 0x80000000u);
            key[t] = kk;
            const unsigned long long pk =
                ((unsigned long long)kk << 12) | (unsigned int)m;
            pmin = pk < pmin ? pk : pmin;
        }
    }

    // wave-level bitonic sort of the 64 per-thread minima (registers only)
    unsigned long long v = pmin;
    #pragma unroll
    for (int kk2 = 2; kk2 <= 64; kk2 <<= 1) {
        #pragma unroll
        for (int j = kk2 >> 1; j > 0; j >>= 1) {
            const unsigned long long o = shfl_xor_u64(v, j);
            const bool up = ((lane & kk2) == 0);
            const bool keepMin = (((lane & j) == 0) == up);
            const unsigned long long mn = v < o ? v : o;
            const unsigned long long mx = v < o ? o : v;
            v = keepMin ? mn : mx;
        }
    }
    if (lane < 21) wm[wave * 21 + lane] = v;
    __syncthreads();

    // exact 21st-smallest of the 256 thread-minima: provable upper bound T
    if (tid < 84) {
        const unsigned long long xv = wm[tid];
        int r = 0;
        for (int j = 0; j < 84; ++j) r += (wm[j] < xv);
        if (r == 20) sT = xv;                      // unique (pk distinct)
    }
    __syncthreads();
    const unsigned long long T = sT;

    // compact candidates <= T (~22-45 expected; contains global top-21)
    #pragma unroll
    for (int t = 0; t < EPT; ++t) {
        const int m = tid * EPT + t;
        const unsigned long long pk =
            ((unsigned long long)key[t] << 12) | (unsigned int)m;
        if (pk <= T) {
            const unsigned int p = atomicAdd(&cnt, 1u);
            if (p < CAND_CAP) cand[p] = pk;
        }
    }
    __syncthreads();

    const int k = *kptr;                           // 20
    const int K1 = k + 1;
    const int cn = cnt < (unsigned)CAND_CAP ? (int)cnt : CAND_CAP;
    if (tid < cn) {
        const unsigned long long xv = cand[tid];
        int r = 0;
        for (int j = 0; j < cn; ++j) r += (cand[j] < xv);
        // rank 0 = dropped first column (matches reference's idx[:,:,0] drop
        // under the identical total order); ranks 1..k = neighbors in order
        if (r <= k) idx21[r] = (int)(xv & 0xFFFu);
    }
    __syncthreads();                               // cand/wm dead after this

    // phase B: gather x rows (rank 0..k) into upool-as-xs
    for (int t = wave; t < K1; t += 4)
        xs[t][lane] = x[((size_t)((b << 12) + idx21[t]) << 6) + lane];
    __syncthreads();

    // dots: t=0 -> f1 (self row @ Wa1), t>=1 -> f2_t (@ Wa2); butterfly reduce
    for (int t = wave; t < K1; t += 4) {
        const float* wv = (t == 0) ? sWa1 : sWa2;
        float p = xs[t][lane] * wv[lane];
        #pragma unroll
        for (int off = 32; off > 0; off >>= 1) p += __shfl_down(p, off, 64);
        if (lane == 0) { if (t == 0) sf1 = p; else aw[t] = p; }
    }
    __syncthreads();

    if (tid == 0) {
        const float f1v = sf1;
        float mx = -FLT_MAX;
        for (int t = 1; t <= k; ++t) {
            float e = f1v + aw[t];
            e = e > 0.f ? e : LRELU_ALPHA * e;
            aw[t] = e;
            mx = fmaxf(mx, e);
        }
        float Z = 0.f;
        for (int t = 1; t <= k; ++t) Z += __expf(aw[t] - mx);
        const float rz = 1.0f / Z;
        for (int t = 1; t <= k; ++t) aw[t] = __expf(aw[t] - mx) * rz;
    }
    __syncthreads();

    // g = attn @ x  (x-space gather)
    float gp = 0.f;
    for (int t = 1 + wave; t <= k; t += 4)
        gp = fmaf(aw[t], xs[t][lane], gp);
    part[wave][lane] = gp;
    __syncthreads();
    if (tid < FD) gs[tid] = part[0][tid] + part[1][tid] + part[2][tid] + part[3][tid];
    __syncthreads();

    // h = g @ W — W from global: coalesced 256B rows, L1/L2-hit (16 KB, hot)
    float hp = 0.f;
    #pragma unroll
    for (int i = 0; i < 16; ++i) {
        const int kk = wave * 16 + i;
        hp = fmaf(gs[kk], W[kk * FD + lane], hp);
    }
    part[wave][lane] = hp;
    __syncthreads();

    if (tid < FD) {
        float h = part[0][tid] + part[1][tid] + part[2][tid] + part[3][tid];
        float pv = fmaf(qx, Wp[0 * FD + tid],
                   fmaf(qy, Wp[1 * FD + tid],
                   fmaf(qz, Wp[2 * FD + tid], bp[tid])));
        h += pv > 0.f ? pv : 0.f;
        out[((size_t)row << 6) + tid] = h > 0.f ? h : expm1f(h);
    }
}

extern "C" void kernel_launch(void* const* d_in, const int* in_sizes, int n_in,
                              void* d_out, int out_size, void* d_ws, size_t ws_size,
                              hipStream_t stream) {
    const float* x   = (const float*)d_in[0];
    const float* pos = (const float*)d_in[1];
    const float* W   = (const float*)d_in[2];
    const float* a   = (const float*)d_in[3];
    const float* Wp  = (const float*)d_in[4];
    const float* bp  = (const float*)d_in[5];
    const int*   kp  = (const int*)d_in[6];
    float* wa  = (float*)d_ws;                     // 128 floats
    float* out = (float*)d_out;

    wa_kernel<<<1, 128, 0, stream>>>(W, a, wa);
    gat_fused<<<8192, 256, 0, stream>>>(x, pos, W, wa, Wp, bp, kp, out);
}